// Round 5
// baseline (176.786 us; speedup 1.0000x reference)
//
#include <hip/hip_runtime.h>

#define B_ 4
#define S_ 2048
#define E_ 1024

typedef __attribute__((ext_vector_type(8))) short short8;
typedef __attribute__((ext_vector_type(4))) float f32x4;

__device__ __forceinline__ unsigned short f2bu(float f) {
  unsigned u = __builtin_bit_cast(unsigned, f);
  u = (u + 0x7FFFu + ((u >> 16) & 1u)) >> 16;
  return (unsigned short)u;
}

__device__ __forceinline__ void gload_lds16(const void* g, void* l) {
  __builtin_amdgcn_global_load_lds(
      (const __attribute__((address_space(1))) void*)g,
      (__attribute__((address_space(3))) void*)l, 16, 0, 0);
}

// ---------------- fp32 -> bf16 convert ----------------
__global__ __launch_bounds__(256) void cvt_f32_bf16(
    const float* __restrict__ in, unsigned short* __restrict__ out, int n) {
  int i = blockIdx.x * 256 + threadIdx.x;
  if (i * 4 >= n) return;
  float4 v = ((const float4*)in)[i];
  ushort4 o;
  o.x = f2bu(v.x); o.y = f2bu(v.y); o.z = f2bu(v.z); o.w = f2bu(v.w);
  ((ushort4*)out)[i] = o;
}

__global__ __launch_bounds__(256) void cvt_w3(
    const float* __restrict__ w0, const float* __restrict__ w1,
    const float* __restrict__ w2, unsigned short* __restrict__ out, int n) {
  int z = blockIdx.z;
  const float* in = (z == 0) ? w0 : (z == 1) ? w1 : w2;
  int i = blockIdx.x * 256 + threadIdx.x;
  if (i * 4 >= n) return;
  float4 v = ((const float4*)in)[i];
  ushort4 o;
  o.x = f2bu(v.x); o.y = f2bu(v.y); o.z = f2bu(v.z); o.w = f2bu(v.w);
  ((ushort4*)(out + (long)z * n))[i] = o;
}

// ================= 8-phase-style deep-pipelined QKV GEMM =================
// C[8192][3072] = xb[8192][1024] * W[3072][1024]^T + bias, routed per segment:
// cols 0-1023 -> Q rowmajor, 1024-2047 -> K rowmajor, 2048-3071 -> V transposed.
// BM=256, BN=128, BK=64, 512 threads (8 waves, 2M x 4N), wave tile 128x32.
// LDS 96KB: bufA[2] 32KB each (256x64 bf16, 128B rows), bufB[2] 16KB each.
// XOR swizzle on LDS reads: colbyte ^= (row&7)<<4; staging keeps LDS dest
// linear (global_load_lds) and pre-swizzles the GLOBAL source column.
// Pipeline ledger (insts/wave, issue order [cA(t) x4, cB(t) x2, cA(t+1) x4]):
//   boundary of iter t: s_waitcnt vmcnt(4)  (tile t landed, cA(t+1) in flight)
//   ph0: read A half0 + B j0 ; issue cB(t+1) x2
//   ph1: read B j1
//   ph2: read A half1
//   ph3: issue cA(t+2) x4   (bufA[t&1] fully consumed after ph2)
// Each phase: [reads/issues] bar; lgkmcnt(0); setprio(1) 8 MFMA setprio(0); bar.
__global__ __launch_bounds__(512, 2) void qkv8(
    const unsigned short* __restrict__ A, const unsigned short* __restrict__ W,
    const float* __restrict__ bq, const float* __restrict__ bk,
    const float* __restrict__ bv,
    unsigned short* __restrict__ Qo, unsigned short* __restrict__ Ko,
    unsigned short* __restrict__ Vt) {
  extern __shared__ char smem[];
  constexpr int NT = 16;  // K=1024 / BK=64
  int tid = threadIdx.x;
  int l = tid & 63, w = tid >> 6;
  int wm = w >> 2, wn = w & 3;
  int tm = blockIdx.y, tn = blockIdx.x;  // 32 x 24

  // staging: sub-block s = w*2+q covers rows s*8+(l>>3); lane col (l&7)*16B.
  // pre-swizzled global source column (elements):
  int scol = 8 * ((l & 7) ^ ((l >> 3) & 7));
  const unsigned short* Ag = A + (long)tm * 256 * 1024 + scol;
  const unsigned short* Bg = W + (long)tn * 128 * 1024 + scol;

#define STG_A(tt, h, q)                                                     \
  gload_lds16(Ag + ((long)(h) * 128 + (w * 2 + (q)) * 8 + (l >> 3)) * 1024  \
                  + (long)(tt) * 64,                                        \
              smem + ((tt) & 1) * 32768 + (h) * 16384 + (w * 2 + (q)) * 1024)
#define STG_B(tt, q)                                                        \
  gload_lds16(Bg + ((long)(w * 2 + (q)) * 8 + (l >> 3)) * 1024              \
                  + (long)(tt) * 64,                                        \
              smem + 65536 + ((tt) & 1) * 16384 + (w * 2 + (q)) * 1024)

  // LDS read offsets (bytes): row*128 + ((kk*64 + (l>>4)*16) ^ ((l&7)<<4))
  int xorc = (l & 7) << 4;
  int c0 = ((l >> 4) * 16) ^ xorc;         // kk=0
  int c1 = (64 + (l >> 4) * 16) ^ xorc;    // kk=1
  int arowbase = (wm * 128 + (l & 15)) * 128;
  int browbase = (wn * 32 + (l & 15)) * 128;

  f32x4 acc[8][2] = {};
  short8 a[4][2], b[2][2];

  // prologue: cA(0), cB(0), cA(1)   [10 insts in flight]
  STG_A(0, 0, 0); STG_A(0, 0, 1); STG_A(0, 1, 0); STG_A(0, 1, 1);
  STG_B(0, 0);    STG_B(0, 1);
  STG_A(1, 0, 0); STG_A(1, 0, 1); STG_A(1, 1, 0); STG_A(1, 1, 1);

#define PHASE_TAIL(h, j)                                                    \
  asm volatile("" ::: "memory");                                            \
  __builtin_amdgcn_s_barrier();                                             \
  asm volatile("s_waitcnt lgkmcnt(0)" ::: "memory");                        \
  __builtin_amdgcn_sched_barrier(0);                                        \
  __builtin_amdgcn_s_setprio(1);                                            \
  _Pragma("unroll")                                                         \
  for (int ii = 0; ii < 4; ii++) {                                          \
    acc[(h) * 4 + ii][j] = __builtin_amdgcn_mfma_f32_16x16x32_bf16(         \
        a[ii][0], b[j][0], acc[(h) * 4 + ii][j], 0, 0, 0);                  \
    acc[(h) * 4 + ii][j] = __builtin_amdgcn_mfma_f32_16x16x32_bf16(         \
        a[ii][1], b[j][1], acc[(h) * 4 + ii][j], 0, 0, 0);                  \
  }                                                                         \
  __builtin_amdgcn_s_setprio(0);                                            \
  __builtin_amdgcn_sched_barrier(0);                                        \
  asm volatile("" ::: "memory");                                            \
  __builtin_amdgcn_s_barrier();

  for (int t = 0; t < NT; ++t) {
    const char* Ad = smem + (t & 1) * 32768;
    const char* Bd = smem + 65536 + (t & 1) * 16384;
    if (t < NT - 1) asm volatile("s_waitcnt vmcnt(4)" ::: "memory");
    else            asm volatile("s_waitcnt vmcnt(0)" ::: "memory");
    __builtin_amdgcn_s_barrier();

    // phase 0: A half0 (i0-3) + B j0; stage cB(t+1)
#pragma unroll
    for (int ii = 0; ii < 4; ii++) {
      a[ii][0] = *(const short8*)(Ad + arowbase + ii * 2048 + c0);
      a[ii][1] = *(const short8*)(Ad + arowbase + ii * 2048 + c1);
    }
    b[0][0] = *(const short8*)(Bd + browbase + c0);
    b[0][1] = *(const short8*)(Bd + browbase + c1);
    if (t + 1 < NT) { STG_B(t + 1, 0); STG_B(t + 1, 1); }
    PHASE_TAIL(0, 0)

    // phase 1: B j1
    b[1][0] = *(const short8*)(Bd + browbase + 2048 + c0);
    b[1][1] = *(const short8*)(Bd + browbase + 2048 + c1);
    PHASE_TAIL(0, 1)

    // phase 2: A half1 (i4-7)
#pragma unroll
    for (int ii = 0; ii < 4; ii++) {
      a[ii][0] = *(const short8*)(Ad + arowbase + 8192 + ii * 2048 + c0);
      a[ii][1] = *(const short8*)(Ad + arowbase + 8192 + ii * 2048 + c1);
    }
    PHASE_TAIL(1, 0)

    // phase 3: stage cA(t+2)
    if (t + 2 < NT) { STG_A(t + 2, 0, 0); STG_A(t + 2, 0, 1);
                      STG_A(t + 2, 1, 0); STG_A(t + 2, 1, 1); }
    PHASE_TAIL(1, 1)
  }

  // epilogue: D col=lane&15, row=(lane>>4)*4+treg  [m89-verified]
  int rh = l >> 4, cl = l & 15;
  int colbase = tn * 128 + wn * 32 + cl;
  long rowbase = (long)tm * 256 + wm * 128 + rh * 4;
  int seg = tn >> 3;  // 0=Q 1=K 2=V (block-uniform)
  const float* bias = (seg == 0) ? bq : (seg == 1) ? bk : bv;
#pragma unroll
  for (int j = 0; j < 2; j++) {
    int c = colbase + j * 16;
    int cm = c & 1023;
    float bv_ = bias[cm];
#pragma unroll
    for (int i = 0; i < 8; i++) {
      long r0 = rowbase + i * 16;
      f32x4 v = acc[i][j];
      if (seg < 2) {
        unsigned short* Ch = seg ? Ko : Qo;
#pragma unroll
        for (int t4 = 0; t4 < 4; t4++)
          Ch[(r0 + t4) * (long)E_ + cm] = f2bu(v[t4] + bv_);
      } else {
        ushort4 pk;
        pk.x = f2bu(v[0] + bv_);
        pk.y = f2bu(v[1] + bv_);
        pk.z = f2bu(v[2] + bv_);
        pk.w = f2bu(v[3] + bv_);
        *(ushort4*)(Vt + (long)cm * (B_ * S_) + r0) = pk;
      }
    }
  }
#undef STG_A
#undef STG_B
#undef PHASE_TAIL
}

// ---------------- B^T GEMM, m97 structure (scores / PV) ----------------
// MODE 1 (SCORES+EXP): lower-tri linear grid (136,1,4); epilogue writes
//                 P' = exp(s/32) bf16 (c<=r else 0) to C0 (lda S_).
// MODE 2 (PV+NORM): A=P' bf16 (lda S_), B=Vt(1024x8192), Keff=(bm+1)*128.
//                 Extra all-ones B-frag accumulates row denom; epilogue divides.
template<int MODE>
__global__ __launch_bounds__(256, 3) void gemm_bt(
    const unsigned short* __restrict__ A, long sAz, int lda,
    const unsigned short* __restrict__ B, long sBz, int ldb,
    void* __restrict__ C0, long sCz, int ldc, int K, float scale) {
  constexpr int BM = 128, BN = 128, BK = 64;
  __shared__ unsigned short lA[BM * BK];
  __shared__ unsigned short lB[BN * BK];
  int bm, bn;
  int bz = blockIdx.z;
  if constexpr (MODE == 1) {
    int t = blockIdx.x;  // 0..135 lower-tri linear
    bm = (int)((sqrtf(8.f * t + 1.f) - 1.f) * 0.5f);
    while ((bm + 1) * (bm + 2) / 2 <= t) bm++;
    while (bm * (bm + 1) / 2 > t) bm--;
    bn = t - bm * (bm + 1) / 2;
  } else {
    bm = blockIdx.y; bn = blockIdx.x;
  }
  const unsigned short* Ab = A + (long)bz * sAz + (long)bm * BM * lda;
  const unsigned short* Bb = B + (long)bz * sBz + (long)bn * BN * ldb;
  int Keff = (MODE == 2) ? min(K, (bm + 1) * BM) : K;

  int tid = threadIdx.x;
  int l = tid & 63, w = tid >> 6;
  int wm = w >> 1, wn = w & 1;

  int srow = l >> 3;
  int schunk = (l & 7) * 8;
  const unsigned short* ga[4];
  const unsigned short* gb[4];
  unsigned short* lad[4];
  unsigned short* lbd[4];
#pragma unroll
  for (int i = 0; i < 4; i++) {
    int seg = i * 4 + w;
    int row = seg * 8 + srow;
    ga[i] = Ab + (long)row * lda + schunk;
    gb[i] = Bb + (long)row * ldb + schunk;
    lad[i] = &lA[seg * 512];
    lbd[i] = &lB[seg * 512];
  }
  int aoff[4], boff[4];
#pragma unroll
  for (int i = 0; i < 4; i++) {
    aoff[i] = (wm * 64 + i * 16 + (l & 15)) * BK + (l >> 4) * 8;
    boff[i] = (wn * 64 + i * 16 + (l & 15)) * BK + (l >> 4) * 8;
  }

  f32x4 acc[4][4] = {};
  f32x4 accd[4] = {};
  short8 ones;
#pragma unroll
  for (int z = 0; z < 8; z++) ones[z] = (short)0x3F80;

  for (int k0 = 0; k0 < Keff; k0 += BK) {
    __syncthreads();
#pragma unroll
    for (int i = 0; i < 4; i++) {
      gload_lds16(ga[i], lad[i]);
      gload_lds16(gb[i], lbd[i]);
    }
#pragma unroll
    for (int i = 0; i < 4; i++) { ga[i] += BK; gb[i] += BK; }
    __syncthreads();
#pragma unroll
    for (int kk = 0; kk < 2; kk++) {
      short8 af[4], bf[4];
#pragma unroll
      for (int i = 0; i < 4; i++) af[i] = *(const short8*)&lA[aoff[i] + kk * 32];
#pragma unroll
      for (int j = 0; j < 4; j++) bf[j] = *(const short8*)&lB[boff[j] + kk * 32];
#pragma unroll
      for (int i = 0; i < 4; i++)
#pragma unroll
        for (int j = 0; j < 4; j++)
          acc[i][j] = __builtin_amdgcn_mfma_f32_16x16x32_bf16(af[i], bf[j], acc[i][j], 0, 0, 0);
      if constexpr (MODE == 2) {
#pragma unroll
        for (int i = 0; i < 4; i++)
          accd[i] = __builtin_amdgcn_mfma_f32_16x16x32_bf16(af[i], ones, accd[i], 0, 0, 0);
      }
    }
  }

  int rh = l >> 4, cl = l & 15;
  long rowbase = (long)bm * BM + wm * 64 + rh * 4;
  int colbase = bn * BN + wn * 64 + cl;

  if constexpr (MODE == 1) {
    unsigned short* Ph = (unsigned short*)C0 + (long)bz * sCz;
#pragma unroll
    for (int j = 0; j < 4; j++) {
      int c = colbase + j * 16;
#pragma unroll
      for (int i = 0; i < 4; i++) {
        int r0 = (int)rowbase + i * 16;
        f32x4 v = acc[i][j];
#pragma unroll
        for (int t = 0; t < 4; t++) {
          int r = r0 + t;
          float p = (c <= r) ? __expf(v[t] * scale) : 0.f;
          Ph[(long)r * ldc + c] = f2bu(p);
        }
      }
    }
  } else {
    float* Cf = (float*)C0 + (long)bz * sCz;
#pragma unroll
    for (int j = 0; j < 4; j++) {
      int c = colbase + j * 16;
#pragma unroll
      for (int i = 0; i < 4; i++) {
        long r0 = rowbase + i * 16;
        f32x4 v = acc[i][j];
        f32x4 d = accd[i];
#pragma unroll
        for (int t = 0; t < 4; t++)
          Cf[(r0 + t) * (long)ldc + c] = v[t] / d[t];
      }
    }
  }
}

// ---------------- host ----------------
extern "C" void kernel_launch(void* const* d_in, const int* in_sizes, int n_in,
                              void* d_out, int out_size, void* d_ws, size_t ws_size,
                              hipStream_t stream) {
  const float* x  = (const float*)d_in[0];
  const float* Wq = (const float*)d_in[2];
  const float* bq = (const float*)d_in[3];
  const float* Wk = (const float*)d_in[4];
  const float* bk = (const float*)d_in[5];
  const float* Wv = (const float*)d_in[6];
  const float* bv = (const float*)d_in[7];
  float* out = (float*)d_out;

  const long NX = (long)B_ * S_ * E_;  // 8388608
  const long NW = (long)E_ * E_;       // 1048576
  unsigned short* xb  = (unsigned short*)d_ws;
  unsigned short* wqb = xb + NX;       // [3072][1024] contiguous (q,k,v)
  unsigned short* Qb  = wqb + 3 * NW;
  unsigned short* Kb  = Qb + NX;
  unsigned short* Vtb = Kb + NX;       // layout [E][B*S]
  unsigned short* Pb  = Vtb + NX;      // [B][S][S] bf16 unnormalized exp-scores

  static int smem_set = 0;
  if (!smem_set) {
    hipFuncSetAttribute((const void*)qkv8,
                        hipFuncAttributeMaxDynamicSharedMemorySize, 98304);
    smem_set = 1;
  }

  cvt_f32_bf16<<<8192, 256, 0, stream>>>(x, xb, (int)NX);
  cvt_w3<<<dim3(1024, 1, 3), 256, 0, stream>>>(Wq, Wk, Wv, wqb, (int)NW);

  // fused QKV, deep-pipelined
  qkv8<<<dim3(24, 32), 512, 98304, stream>>>(
      xb, wqb, bq, bk, bv, Qb, Kb, Vtb);

  // P' = exp(Q K^T / 32) (causal, bf16), lower-tri linear grid
  gemm_bt<1><<<dim3(136, 1, 4), 256, 0, stream>>>(
      Qb, (long)S_ * E_, E_, Kb, (long)S_ * E_, E_,
      Pb, (long)S_ * S_, S_, E_, 0.03125f);

  // out = (P' V) / rowsum(P') : A = P', B = Vt (N=E, K=S), denom via ones-MFMA
  gemm_bt<2><<<dim3(8, 16, 4), 256, 0, stream>>>(
      Pb, (long)S_ * S_, S_,
      Vtb, (long)S_, B_ * S_,
      out, (long)S_ * E_, E_, S_, 1.f);
}